// Round 19
// baseline (2176.538 us; speedup 1.0000x reference)
//
#include <hip/hip_runtime.h>

#define T_DIM 512
#define B_DIM 256
#define I_DIM 64
#define H_DIM 128
#define P_DIM 256
#define O_DIM 50

typedef _Float16 half8 __attribute__((ext_vector_type(8)));
typedef _Float16 half4 __attribute__((ext_vector_type(4)));
typedef float f32x4 __attribute__((ext_vector_type(4)));

#define GLOAD_LDS16(G, L)                                                      \
  __builtin_amdgcn_global_load_lds(                                            \
      (const __attribute__((address_space(1))) void*)(G),                      \
      (__attribute__((address_space(3))) void*)(L), 16, 0, 0)

__device__ __forceinline__ float sigm(float x) {
  return __builtin_amdgcn_rcpf(1.f + __expf(-x));
}
__device__ __forceinline__ float tanh_f(float x) {
  x = fminf(20.f, fmaxf(-20.f, x));
  float e = __expf(2.f * x);
  return (e - 1.f) * __builtin_amdgcn_rcpf(e + 1.f);
}

// ---------------- elementwise fp32 -> fp16 ----------------
__global__ void cvt_k(const float* __restrict__ s, _Float16* __restrict__ d, long n) {
  long i = (long)blockIdx.x * blockDim.x + threadIdx.x;
  long st = (long)gridDim.x * blockDim.x;
  for (; i < n; i += st) d[i] = (_Float16)s[i];
}

// fused 6-tensor weight conversion (one launch instead of six)
__global__ void cvt6_k(const float* a0, _Float16* b0, int n0, const float* a1, _Float16* b1,
                       int n1, const float* a2, _Float16* b2, int n2, const float* a3,
                       _Float16* b3, int n3, const float* a4, _Float16* b4, int n4,
                       const float* a5, _Float16* b5, int n5) {
  int i = blockIdx.x * blockDim.x + threadIdx.x;
  int st = gridDim.x * blockDim.x;
  int total = n0 + n1 + n2 + n3 + n4 + n5;
  for (; i < total; i += st) {
    int j = i;
    if (j < n0) { b0[j] = (_Float16)a0[j]; continue; }
    j -= n0;
    if (j < n1) { b1[j] = (_Float16)a1[j]; continue; }
    j -= n1;
    if (j < n2) { b2[j] = (_Float16)a2[j]; continue; }
    j -= n2;
    if (j < n3) { b3[j] = (_Float16)a3[j]; continue; }
    j -= n3;
    if (j < n4) { b4[j] = (_Float16)a4[j]; continue; }
    j -= n4;
    b5[j] = (_Float16)a5[j];
  }
}

// ---------------- fused: xmean over t + skip_mean = xmean @ Ws^T + bs ----------------
__global__ void xmean_skip_k(const float* __restrict__ x, const float* __restrict__ Wsk,
                             const float* __restrict__ bsk, float* __restrict__ skipm) {
  __shared__ float xs[4][64];
  __shared__ float xmf[64];
  const int b = blockIdx.x, tid = threadIdx.x;  // 256 threads
  const int i = tid & 63, q = tid >> 6;
  float s = 0.f;
  for (int t = q * 128; t < (q + 1) * 128; ++t) s += x[((long)t * B_DIM + b) * I_DIM + i];
  xs[q][i] = s;
  __syncthreads();
  if (tid < 64) xmf[tid] = (xs[0][tid] + xs[1][tid] + xs[2][tid] + xs[3][tid]) * (1.0f / T_DIM);
  __syncthreads();
  float acc = bsk[tid];
  for (int k = 0; k < I_DIM; ++k) acc += xmf[k] * Wsk[tid * I_DIM + k];
  skipm[b * P_DIM + tid] = acc;
}

// zero gsum/gss/aggT/flags in one launch (blocks 0-255: aggT, 256: gsum/gss, 257: flags)
__global__ void zeroAll_k(float* aggT, float* gsum, float* gss, int* flags) {
  int b = blockIdx.x, t = threadIdx.x;
  if (b < 256) {
    aggT[b * 256 + t] = 0.f;
  } else if (b == 256) {
    gsum[t] = 0.f;
    gss[t] = 0.f;
  } else if (t < 64) {
    flags[t] = 0;
  }
}

// fold BN affine into Wcih (per-column scale) + bias; BN scalars computed inline
__global__ void fold_k(const float* __restrict__ Wcih, const float* __restrict__ bcih,
                       const float* __restrict__ gsum, const float* __restrict__ gss,
                       const float* __restrict__ gamma, const float* __restrict__ beta,
                       _Float16* __restrict__ WF, float* __restrict__ bF) {
  __shared__ float red[256];
  int n = blockIdx.x, k = threadIdx.x;
  const float inv = 1.0f / ((float)T_DIM * (float)B_DIM);
  float m = gsum[k] * inv;
  float v = gss[k] * inv - m * m;
  float rs = rsqrtf(v + 1e-5f);
  float sc = gamma[k] * rs;
  float tn = beta[k] - m * sc;
  float wv = Wcih[n * 256 + k];
  WF[n * 256 + k] = (_Float16)(wv * sc);
  red[k] = wv * tn;
  __syncthreads();
  for (int s = 128; s > 0; s >>= 1) {
    if (k < s) red[k] += red[k + s];
    __syncthreads();
  }
  if (k == 0) bF[n] = bcih[n] + red[0];
}

// ---------------- fp16 MFMA GEMM: C = A[M,K] @ W[N,K]^T + bias (+bias2 n<n2lim)
// transN=0: C row-major [M][N]; if gsum!=null also accumulate BN stats per column.
// transN=1: C = [bblk][t][N][16] with M = t*256+b, bblk=b>>4  (block-major for scans)
__global__ __launch_bounds__(256) void gemm_k(
    const _Float16* __restrict__ A, const _Float16* __restrict__ W,
    const float* __restrict__ bias, const float* __restrict__ bias2, int n2lim,
    _Float16* __restrict__ C, int M, int N, int K, int transN,
    float* __restrict__ gsum, float* __restrict__ gss) {
  __shared__ __align__(16) _Float16 As[128 * 64];
  __shared__ __align__(16) _Float16 Bs[128 * 64];
  const int tid = threadIdx.x;
  const int l = tid & 63;
  const int w = tid >> 6;
  const int wr = w >> 1, wc = w & 1;
  const int lrow = l & 15, lk = l >> 4;
  const long bm = blockIdx.x, bn = blockIdx.y;

  f32x4 z = {0.f, 0.f, 0.f, 0.f};
  f32x4 acc[4][4];
#pragma unroll
  for (int m = 0; m < 4; ++m)
#pragma unroll
    for (int n = 0; n < 4; ++n) acc[m][n] = z;

  for (int k0 = 0; k0 < K; k0 += 64) {
    if (k0) __syncthreads();
#pragma unroll
    for (int it = 0; it < 4; ++it) {
      const int lin = it * 256 + tid;
      const int row = lin >> 3, slot = lin & 7;
      const int scol = (slot ^ (row & 7)) << 3;  // pre-swizzled global source
      GLOAD_LDS16(A + (bm * 128 + row) * (long)K + k0 + scol, (_Float16*)As + (size_t)lin * 8);
      GLOAD_LDS16(W + (bn * 128 + row) * (long)K + k0 + scol, (_Float16*)Bs + (size_t)lin * 8);
    }
    __syncthreads();
#pragma unroll
    for (int kk = 0; kk < 2; ++kk) {
      half8 af[4], wfr[4];
#pragma unroll
      for (int m = 0; m < 4; ++m) {
        const int row = wr * 64 + m * 16 + lrow;
        af[m] = *(const half8*)((const char*)As +
                                ((row * 128 + (kk * 32 + lk * 8) * 2) ^ ((row & 7) << 4)));
      }
#pragma unroll
      for (int n = 0; n < 4; ++n) {
        const int row = wc * 64 + n * 16 + lrow;
        wfr[n] = *(const half8*)((const char*)Bs +
                                 ((row * 128 + (kk * 32 + lk * 8) * 2) ^ ((row & 7) << 4)));
      }
#pragma unroll
      for (int m = 0; m < 4; ++m)
#pragma unroll
        for (int n = 0; n < 4; ++n)
          acc[m][n] = __builtin_amdgcn_mfma_f32_16x16x32_f16(af[m], wfr[n], acc[m][n], 0, 0, 0);
    }
  }
  if (transN) {
    const long tIdx = bm >> 1;  // B=256, 128-row tiles
    const long TCH = M >> 8;
#pragma unroll
    for (int n = 0; n < 4; ++n) {
      const int gn = (int)bn * 128 + wc * 64 + n * 16 + lrow;
      float bv = 0.f;
      if (bias) bv += bias[gn];
      if (bias2 && gn < n2lim) bv += bias2[gn];
#pragma unroll
      for (int m = 0; m < 4; ++m) {
        half4 v;
#pragma unroll
        for (int r = 0; r < 4; ++r) v[r] = (_Float16)(acc[m][n][r] + bv);
        const int blk = (int)(bm & 1) * 8 + wr * 4 + m;
        *(half4*)(C + ((blk * TCH + tIdx) * N + gn) * 16 + lk * 4) = v;
      }
    }
  } else {
#pragma unroll
    for (int n = 0; n < 4; ++n) {
      const int gn = (int)bn * 128 + wc * 64 + n * 16 + lrow;
      float bv = 0.f;
      if (bias) bv += bias[gn];
      if (bias2 && gn < n2lim) bv += bias2[gn];
      float sm = 0.f, sq = 0.f;
#pragma unroll
      for (int m = 0; m < 4; ++m)
#pragma unroll
        for (int r = 0; r < 4; ++r) {
          const long gm = bm * 128 + wr * 64 + m * 16 + lk * 4 + r;
          _Float16 pv = (_Float16)(acc[m][n][r] + bv);
          C[gm * (long)N + gn] = pv;
          float pf = (float)pv;
          sm += pf;
          sq += pf * pf;
        }
      if (gsum) {
        sm += __shfl_xor(sm, 16);
        sm += __shfl_xor(sm, 32);
        sq += __shfl_xor(sq, 16);
        sq += __shfl_xor(sq, 32);
        if (lk == 0) {
          atomicAdd(&gsum[gn], sm);
          atomicAdd(&gss[gn], sq);
        }
      }
    }
  }
}

// ---------------- producer/consumer 2-layer GRU scan across 32 blocks --------------
// Producer publishes every 32 steps; xp prefetch distance = 2 steps (n-gate fragment
// saved to locals before reissuing the same-parity buffer's load).
__global__ __launch_bounds__(512, 1) void scan01_pipe(
    const _Float16* __restrict__ xp0T,   // [bblk][T][384][16] incl. bih0 + bhh0(r,z)
    const _Float16* __restrict__ Whh0h,  // [384][128] fp16
    const _Float16* __restrict__ Wih1h,  // [384][128] fp16
    const _Float16* __restrict__ Whh1h,  // [384][128] fp16
    const float* __restrict__ bhh0, const float* __restrict__ bih1,
    const float* __restrict__ bhh1,
    const float* __restrict__ h0init,  // [2][B][128]
    _Float16* __restrict__ y0buf,      // [16][T][16][128]
    _Float16* __restrict__ h1buf,      // [T*256][128] row-major
    int* flags) {
  __shared__ __align__(16) _Float16 hL[2][16 * 128];
  const int tid = threadIdx.x;
  const int l = tid & 63, w = tid >> 6;  // 8 waves
  const int lrow = l & 15, lk = l >> 4;
  const int bblk = blockIdx.x & 15;
  const int rbase = bblk * 16;
  const int p = w * 16 + lrow;

  if (blockIdx.x < 16) {
    // ================= producer: layer0 =================
    half8 wf0[3][4];
#pragma unroll
    for (int g = 0; g < 3; ++g)
#pragma unroll
      for (int kk = 0; kk < 4; ++kk)
        wf0[g][kk] = *(const half8*)(Whh0h + (size_t)(g * 128 + p) * 128 + kk * 32 + lk * 8);
    const float bN0 = bhh0[2 * H_DIM + p];
    float h0r[4];
#pragma unroll
    for (int r = 0; r < 4; ++r) h0r[r] = h0init[(rbase + lk * 4 + r) * H_DIM + p];
    for (int i = tid; i < 16 * 128; i += 512) {
      int row = i >> 7, pp = i & 127;
      int byte = (row * 256 + pp * 2) ^ ((row & 7) << 4);
      *(_Float16*)((char*)hL[1] + byte) = (_Float16)h0init[(rbase + row) * H_DIM + pp];
    }
    __syncthreads();

    half4 xA[3], xB[3];
    auto loadx = [&](half4(&X)[3], int tt) {
#pragma unroll
      for (int g = 0; g < 3; ++g)
        X[g] = *(const half4*)(xp0T + (((long)bblk * T_DIM + tt) * 384 + g * 128 + p) * 16 +
                               lk * 4);
    };
    // XC holds data for step t; after consuming r/z (acc init) and saving the
    // n-gate fragment, XC is reloaded with data for t+2 (same parity).
    auto pstep = [&](int t, half4(&XC)[3]) {
      char* cur = (char*)hL[(t & 1) ^ 1];
      char* nxt = (char*)hL[t & 1];
      f32x4 aR, aZ, aN;
#pragma unroll
      for (int r = 0; r < 4; ++r) {
        aR[r] = (float)XC[0][r];
        aZ[r] = (float)XC[1][r];
        aN[r] = 0.f;
      }
      half4 xn = XC[2];                              // n-gate x, consumed late
      loadx(XC, (t + 2 < T_DIM) ? t + 2 : T_DIM - 1);  // prefetch distance 2
      half8 af[4];
#pragma unroll
      for (int kk = 0; kk < 4; ++kk) {
        int byte = (lrow * 256 + (kk * 32 + lk * 8) * 2) ^ ((lrow & 7) << 4);
        af[kk] = *(const half8*)(cur + byte);
      }
#pragma unroll
      for (int kk = 0; kk < 4; ++kk) {
        aR = __builtin_amdgcn_mfma_f32_16x16x32_f16(af[kk], wf0[0][kk], aR, 0, 0, 0);
        aZ = __builtin_amdgcn_mfma_f32_16x16x32_f16(af[kk], wf0[1][kk], aZ, 0, 0, 0);
        aN = __builtin_amdgcn_mfma_f32_16x16x32_f16(af[kk], wf0[2][kk], aN, 0, 0, 0);
      }
#pragma unroll
      for (int r = 0; r < 4; ++r) {
        float rg = sigm(aR[r]);
        float zg = sigm(aZ[r]);
        float ng = tanh_f((float)xn[r] + rg * (aN[r] + bN0));
        float hv = ng + zg * (h0r[r] - ng);
        h0r[r] = hv;
        int row = lk * 4 + r;
        int byte = (row * 256 + p * 2) ^ ((row & 7) << 4);
        *(_Float16*)(nxt + byte) = (_Float16)hv;
        y0buf[((size_t)(bblk * T_DIM + t) * 16 + row) * 128 + p] = (_Float16)hv;
      }
      if ((t & 31) == 31) {
        __threadfence();  // drain y0 stores (device scope) before publishing
        __syncthreads();  // all threads fenced
        if (tid == 0)
          __hip_atomic_store(&flags[bblk], t + 1, __ATOMIC_RELEASE, __HIP_MEMORY_SCOPE_AGENT);
      } else {
        __syncthreads();
      }
    };
    loadx(xA, 0);
    loadx(xB, 1);
    for (int t = 0; t < T_DIM; t += 2) {
      pstep(t, xA);
      pstep(t + 1, xB);
    }
  } else {
    // ================= consumer: layer1 =================
    half8 wf1x[3][4], wf1h[3][4];
#pragma unroll
    for (int g = 0; g < 3; ++g)
#pragma unroll
      for (int kk = 0; kk < 4; ++kk) {
        const size_t ro = (size_t)(g * 128 + p) * 128 + kk * 32 + lk * 8;
        wf1x[g][kk] = *(const half8*)(Wih1h + ro);
        wf1h[g][kk] = *(const half8*)(Whh1h + ro);
      }
    const float bR1 = bih1[p] + bhh1[p];
    const float bZ1 = bih1[H_DIM + p] + bhh1[H_DIM + p];
    const float bX1 = bih1[2 * H_DIM + p];
    const float bN1 = bhh1[2 * H_DIM + p];
    float h1r[4];
#pragma unroll
    for (int r = 0; r < 4; ++r)
      h1r[r] = h0init[B_DIM * H_DIM + (rbase + lk * 4 + r) * H_DIM + p];
    for (int i = tid; i < 16 * 128; i += 512) {
      int row = i >> 7, pp = i & 127;
      int byte = (row * 256 + pp * 2) ^ ((row & 7) << 4);
      *(_Float16*)((char*)hL[1] + byte) =
          (_Float16)h0init[B_DIM * H_DIM + (rbase + row) * H_DIM + pp];
    }
    __syncthreads();

    const _Float16* yb = y0buf + (size_t)bblk * T_DIM * 16 * 128;
    int avail = 0;
    auto wait_for = [&](int target) {
      if (avail < target) {
        do {
          __builtin_amdgcn_s_sleep(2);
          avail = __hip_atomic_load(&flags[bblk], __ATOMIC_ACQUIRE, __HIP_MEMORY_SCOPE_AGENT);
        } while (avail < target);
      }
    };
    auto loady = [&](half8(&Y)[4], int tt) {
#pragma unroll
      for (int kk = 0; kk < 4; ++kk)
        Y[kk] = *(const half8*)(yb + ((size_t)tt * 16 + lrow) * 128 + kk * 32 + lk * 8);
    };
    auto cstep = [&](int t, half8(&YC)[4], half8(&YN)[4]) {
      wait_for((t + 2 < T_DIM) ? (t + 2) : T_DIM);  // covers prefetch of t+1
      loady(YN, (t + 1 < T_DIM) ? t + 1 : T_DIM - 1);
      char* cur = (char*)hL[(t & 1) ^ 1];
      char* nxt = (char*)hL[t & 1];
      f32x4 aRx = {bR1, bR1, bR1, bR1};
      f32x4 aZx = {bZ1, bZ1, bZ1, bZ1};
      f32x4 aX = {bX1, bX1, bX1, bX1};
      f32x4 aRh = {0.f, 0.f, 0.f, 0.f};
      f32x4 aZh = {0.f, 0.f, 0.f, 0.f};
      f32x4 aH = {0.f, 0.f, 0.f, 0.f};
      half8 ah[4];
#pragma unroll
      for (int kk = 0; kk < 4; ++kk) {
        int byte = (lrow * 256 + (kk * 32 + lk * 8) * 2) ^ ((lrow & 7) << 4);
        ah[kk] = *(const half8*)(cur + byte);
      }
#pragma unroll
      for (int kk = 0; kk < 4; ++kk) {
        aRx = __builtin_amdgcn_mfma_f32_16x16x32_f16(YC[kk], wf1x[0][kk], aRx, 0, 0, 0);
        aZx = __builtin_amdgcn_mfma_f32_16x16x32_f16(YC[kk], wf1x[1][kk], aZx, 0, 0, 0);
        aX = __builtin_amdgcn_mfma_f32_16x16x32_f16(YC[kk], wf1x[2][kk], aX, 0, 0, 0);
        aRh = __builtin_amdgcn_mfma_f32_16x16x32_f16(ah[kk], wf1h[0][kk], aRh, 0, 0, 0);
        aZh = __builtin_amdgcn_mfma_f32_16x16x32_f16(ah[kk], wf1h[1][kk], aZh, 0, 0, 0);
        aH = __builtin_amdgcn_mfma_f32_16x16x32_f16(ah[kk], wf1h[2][kk], aH, 0, 0, 0);
      }
#pragma unroll
      for (int r = 0; r < 4; ++r) {
        float rg = sigm(aRx[r] + aRh[r]);
        float zg = sigm(aZx[r] + aZh[r]);
        float ng = tanh_f(aX[r] + rg * (aH[r] + bN1));
        float hv = ng + zg * (h1r[r] - ng);
        h1r[r] = hv;
        int row = lk * 4 + r;
        int byte = (row * 256 + p * 2) ^ ((row & 7) << 4);
        *(_Float16*)(nxt + byte) = (_Float16)hv;
        h1buf[((long)t * B_DIM + rbase + row) * 128 + p] = (_Float16)hv;
      }
      __syncthreads();
    };
    half8 yA[4], yB[4];
    wait_for(2);
    loady(yA, 0);
    for (int t = 0; t < T_DIM; t += 2) {
      cstep(t, yA, yB);
      cstep(t + 1, yB, yA);
    }
  }
}

// ---------------- GRUCell scan (P=256): 16 blocks x 8 waves ------------------------
// xp prefetch distance = 2 steps (n-gate fragments saved to locals first).
__global__ __launch_bounds__(512, 1) void scan_cell(
    const _Float16* __restrict__ xpT,  // [bblk][TC][768][16] incl. folded biases
    _Float16* __restrict__ hT,         // [TC][256][B] (chunk-offset applied)
    float* __restrict__ hst, const _Float16* __restrict__ Whh,
    const float* __restrict__ bhh, int TC, int first) {
  __shared__ __align__(16) _Float16 hL[2][16 * 256];
  __shared__ __align__(16) _Float16 WL[768 * 64];  // K-slice [192,256) of Wchh, swizzled
  const int tid = threadIdx.x;
  const int l = tid & 63, w = tid >> 6;  // 8 waves
  const int lrow = l & 15, lk = l >> 4;
  const int rbase = blockIdx.x * 16;

  half8 wf[6][6];  // kk 0..5 resident; kk 6..7 from LDS
#pragma unroll
  for (int g = 0; g < 3; ++g)
#pragma unroll
    for (int c = 0; c < 2; ++c) {
      const int nt = g * 16 + 2 * w + c;
#pragma unroll
      for (int kk = 0; kk < 6; ++kk)
        wf[g * 2 + c][kk] =
            *(const half8*)(Whh + (size_t)(nt * 16 + lrow) * P_DIM + kk * 32 + lk * 8);
    }
  for (int q = tid; q < 768 * 8; q += 512) {
    int row = q >> 3, slot = q & 7;
    int scol = (slot ^ (row & 7)) << 3;
    *(half8*)((char*)WL + (size_t)q * 16) = *(const half8*)(Whh + (size_t)row * P_DIM + 192 + scol);
  }
  float bN[2];
#pragma unroll
  for (int c = 0; c < 2; ++c) bN[c] = bhh[2 * P_DIM + 32 * w + 16 * c + lrow];

  float h[2][4];
#pragma unroll
  for (int c = 0; c < 2; ++c)
#pragma unroll
    for (int r = 0; r < 4; ++r)
      h[c][r] = first ? 0.f : hst[(rbase + lk * 4 + r) * P_DIM + 32 * w + 16 * c + lrow];
  for (int i = tid; i < 16 * 256; i += 512) {
    int row = i >> 8, pp = i & 255;
    float hv = first ? 0.f : hst[(rbase + row) * P_DIM + pp];
    int byte = (row * 512 + pp * 2) ^ ((row & 7) << 4);
    *(_Float16*)((char*)hL[0] + byte) = (_Float16)hv;
  }
  __syncthreads();

  half4 xA[3][2], xB[3][2];
  auto loadx = [&](half4(&X)[3][2], int tt) {
#pragma unroll
    for (int g = 0; g < 3; ++g)
#pragma unroll
      for (int c = 0; c < 2; ++c)
        X[g][c] = *(const half4*)(xpT +
                                  (((long)blockIdx.x * TC + tt) * 768 + g * 256 + 32 * w + 16 * c +
                                   lrow) * 16 + lk * 4);
  };
  auto step = [&](int tt, half4(&XC)[3][2]) {
    char* hCur = (char*)hL[tt & 1];
    char* hNxt = (char*)hL[(tt & 1) ^ 1];
    half8 af[4];
    f32x4 acc[3][2];
#pragma unroll
    for (int c = 0; c < 2; ++c)
#pragma unroll
      for (int r = 0; r < 4; ++r) {
        acc[0][c][r] = (float)XC[0][c][r];
        acc[1][c][r] = (float)XC[1][c][r];
        acc[2][c][r] = 0.f;
      }
    half4 xn0 = XC[2][0], xn1 = XC[2][1];            // n-gate x, consumed late
    loadx(XC, (tt + 2 < TC) ? tt + 2 : TC - 1);      // prefetch distance 2
#pragma unroll
    for (int kk = 0; kk < 4; ++kk) {
      int byte = (lrow * 512 + (kk * 32 + lk * 8) * 2) ^ ((lrow & 7) << 4);
      af[kk] = *(const half8*)(hCur + byte);
    }
#pragma unroll
    for (int g = 0; g < 3; ++g)
#pragma unroll
      for (int c = 0; c < 2; ++c)
#pragma unroll
        for (int kk = 0; kk < 4; ++kk)
          acc[g][c] =
              __builtin_amdgcn_mfma_f32_16x16x32_f16(af[kk], wf[g * 2 + c][kk], acc[g][c], 0, 0, 0);
#pragma unroll
    for (int kk = 0; kk < 4; ++kk) {
      int byte = (lrow * 512 + ((kk + 4) * 32 + lk * 8) * 2) ^ ((lrow & 7) << 4);
      af[kk] = *(const half8*)(hCur + byte);
    }
#pragma unroll
    for (int g = 0; g < 3; ++g)
#pragma unroll
      for (int c = 0; c < 2; ++c) {
        const int nt = g * 16 + 2 * w + c;
        const int wrow = nt * 16 + lrow;
        f32x4 a = acc[g][c];
        a = __builtin_amdgcn_mfma_f32_16x16x32_f16(af[0], wf[g * 2 + c][4], a, 0, 0, 0);
        a = __builtin_amdgcn_mfma_f32_16x16x32_f16(af[1], wf[g * 2 + c][5], a, 0, 0, 0);
        half8 w6 = *(const half8*)((char*)WL + ((wrow * 128 + lk * 16) ^ ((wrow & 7) << 4)));
        half8 w7 = *(const half8*)((char*)WL + ((wrow * 128 + 64 + lk * 16) ^ ((wrow & 7) << 4)));
        a = __builtin_amdgcn_mfma_f32_16x16x32_f16(af[2], w6, a, 0, 0, 0);
        a = __builtin_amdgcn_mfma_f32_16x16x32_f16(af[3], w7, a, 0, 0, 0);
        acc[g][c] = a;
      }
#pragma unroll
    for (int c = 0; c < 2; ++c) {
      half4 xn = c ? xn1 : xn0;
      half4 hv4;
#pragma unroll
      for (int r = 0; r < 4; ++r) {
        float rg = sigm(acc[0][c][r]);
        float zg = sigm(acc[1][c][r]);
        float ng = tanh_f((float)xn[r] + rg * (acc[2][c][r] + bN[c]));
        float hv = ng + zg * (h[c][r] - ng);
        h[c][r] = hv;
        hv4[r] = (_Float16)hv;
        const int row = lk * 4 + r, pp = 32 * w + 16 * c + lrow;
        int byte = (row * 512 + pp * 2) ^ ((row & 7) << 4);
        *(_Float16*)(hNxt + byte) = hv4[r];
      }
      *(half4*)(hT + ((long)tt * 256 + 32 * w + 16 * c + lrow) * 256 + rbase + lk * 4) = hv4;
    }
    __syncthreads();
  };
  loadx(xA, 0);
  loadx(xB, (1 < TC) ? 1 : 0);
  for (int t = 0; t < TC; t += 2) {
    step(t, xA);
    step(t + 1, xB);
  }
#pragma unroll
  for (int c = 0; c < 2; ++c)
#pragma unroll
    for (int r = 0; r < 4; ++r)
      hst[(rbase + lk * 4 + r) * P_DIM + 32 * w + 16 * c + lrow] = h[c][r];
}

// ---------------- gelu + mean over t (parallel over t-chunks) ----------------
__global__ void gelu_mean_k(const _Float16* __restrict__ hT, float* __restrict__ aggT) {
  int p = blockIdx.x, b = threadIdx.x;  // 256x8 blocks x 256 threads
  int t0 = blockIdx.y * 64;
  float s = 0.f;
  for (int t = t0; t < t0 + 64; ++t) {
    float v = (float)hT[((long)t * P_DIM + p) * B_DIM + b];
    s += 0.5f * v * (1.f + erff(v * 0.70710678118f));
  }
  atomicAdd(&aggT[p * B_DIM + b], s);
}

// ---------------- final: out = (aggT/T + skipm) @ Wf^T + bf ----------------
__global__ void final_k(const float* __restrict__ aggT, const float* __restrict__ skipm,
                        const float* __restrict__ Wf, const float* __restrict__ bfb,
                        float* __restrict__ out) {
  int b = blockIdx.x, o = threadIdx.x;  // 64 threads
  if (o >= O_DIM) return;
  float s = bfb[o];
  for (int p = 0; p < P_DIM; ++p)
    s += (aggT[p * B_DIM + b] * (1.0f / T_DIM) + skipm[b * P_DIM + p]) * Wf[o * P_DIM + p];
  out[b * O_DIM + o] = s;
}

extern "C" void kernel_launch(void* const* d_in, const int* in_sizes, int n_in, void* d_out,
                              int out_size, void* d_ws, size_t ws_size, hipStream_t stream) {
  const float* x = (const float*)d_in[0];
  const float* h0 = (const float*)d_in[1];
  const float* Wih0 = (const float*)d_in[2];
  const float* Whh0f = (const float*)d_in[3];
  const float* bih0 = (const float*)d_in[4];
  const float* bhh0 = (const float*)d_in[5];
  const float* Wih1 = (const float*)d_in[6];
  const float* Whh1f = (const float*)d_in[7];
  const float* bih1 = (const float*)d_in[8];
  const float* bhh1 = (const float*)d_in[9];
  const float* Wp = (const float*)d_in[10];
  const float* bp = (const float*)d_in[11];
  const float* gamma = (const float*)d_in[12];
  const float* beta = (const float*)d_in[13];
  const float* Wcih = (const float*)d_in[14];
  const float* Wchhf = (const float*)d_in[15];
  const float* bcih = (const float*)d_in[16];
  const float* bchh = (const float*)d_in[17];
  const float* Wsk = (const float*)d_in[18];
  const float* bsk = (const float*)d_in[19];
  const float* Wf = (const float*)d_in[20];
  const float* bfb = (const float*)d_in[21];
  float* out = (float*)d_out;

  char* wsp = (char*)d_ws;
  size_t off = 0;
  auto alloc = [&](size_t b) -> void* {
    void* p = wsp + off;
    off = (off + b + 255) & ~(size_t)255;
    return p;
  };
  _Float16* xh = (_Float16*)alloc((size_t)T_DIM * B_DIM * I_DIM * 2);
  _Float16* wih0 = (_Float16*)alloc(384 * 64 * 2);
  _Float16* whh0 = (_Float16*)alloc(384 * 128 * 2);
  _Float16* wih1 = (_Float16*)alloc(384 * 128 * 2);
  _Float16* whh1 = (_Float16*)alloc(384 * 128 * 2);
  _Float16* wp = (_Float16*)alloc(256 * 128 * 2);
  _Float16* wcihF = (_Float16*)alloc(768 * 256 * 2);
  _Float16* wchh = (_Float16*)alloc(768 * 256 * 2);
  _Float16* proj = (_Float16*)alloc((size_t)T_DIM * B_DIM * P_DIM * 2);  // also y0buf
  _Float16* hT = (_Float16*)alloc((size_t)T_DIM * B_DIM * P_DIM * 2);    // also h1buf
  float* hstc = (float*)alloc(B_DIM * P_DIM * 4);
  float* aggT = (float*)alloc(B_DIM * P_DIM * 4);
  float* skipm = (float*)alloc(B_DIM * P_DIM * 4);
  float* gsum = (float*)alloc(256 * 4);
  float* gss = (float*)alloc(256 * 4);
  float* bcihF = (float*)alloc(768 * 4);
  int* flags = (int*)alloc(64 * 4);

  _Float16* y0buf = proj;  // dead before gemmP writes proj
  _Float16* h1buf = hT;    // dead before scan_cell writes hT

  const size_t xp0_bytes = (size_t)T_DIM * 384 * B_DIM * 2;
  int TC2 = 512;
  while (TC2 > 32 && off + ((size_t)TC2 * B_DIM * 768 * 2 > xp0_bytes
                                ? (size_t)TC2 * B_DIM * 768 * 2
                                : xp0_bytes) >
                         ws_size)
    TC2 >>= 1;
  size_t xpb_bytes = (size_t)TC2 * B_DIM * 768 * 2;
  if (xpb_bytes < xp0_bytes) xpb_bytes = xp0_bytes;
  _Float16* xpb = (_Float16*)alloc(xpb_bytes);
  const int nc2 = T_DIM / TC2;
  const int M2 = TC2 * B_DIM;

  cvt_k<<<dim3(2048), dim3(256), 0, stream>>>(x, xh, (long)T_DIM * B_DIM * I_DIM);
  cvt6_k<<<dim3(512), dim3(256), 0, stream>>>(Wih0, wih0, 384 * 64, Whh0f, whh0, 384 * 128, Wih1,
                                              wih1, 384 * 128, Whh1f, whh1, 384 * 128, Wp, wp,
                                              256 * 128, Wchhf, wchh, 768 * 256);

  xmean_skip_k<<<B_DIM, P_DIM, 0, stream>>>(x, Wsk, bsk, skipm);
  zeroAll_k<<<dim3(258), dim3(256), 0, stream>>>(aggT, gsum, gss, flags);

  // xp0 for all T (input projection layer 0), block-major [bblk][t][384][16]
  gemm_k<<<dim3(T_DIM * B_DIM / 128, 3), 256, 0, stream>>>(
      xh, wih0, bih0, bhh0, 2 * H_DIM, xpb, T_DIM * B_DIM, 3 * H_DIM, I_DIM, 1, nullptr, nullptr);
  // producer/consumer 2-layer scan across 32 blocks
  scan01_pipe<<<32, 512, 0, stream>>>(xpb, whh0, wih1, whh1, bhh0, bih1, bhh1, h0, y0buf, h1buf,
                                      flags);
  // proj = h1 @ Wp^T + bp (row-major out) with fused BN-stats accumulation
  gemm_k<<<dim3(T_DIM * B_DIM / 128, 2), 256, 0, stream>>>(
      h1buf, wp, bp, (const float*)nullptr, 0, proj, T_DIM * B_DIM, P_DIM, H_DIM, 0, gsum, gss);
  // fold BN (scalars computed inline) into Wcih + bias
  fold_k<<<768, 256, 0, stream>>>(Wcih, bcih, gsum, gss, gamma, beta, wcihF, bcihF);
  for (int c = 0; c < nc2; ++c) {
    const _Float16* pc = proj + (size_t)c * TC2 * B_DIM * P_DIM;
    gemm_k<<<dim3(M2 / 128, 6), 256, 0, stream>>>(pc, wcihF, bcihF, bchh, 2 * P_DIM, xpb, M2,
                                                  3 * P_DIM, P_DIM, 1, nullptr, nullptr);
    scan_cell<<<16, 512, 0, stream>>>(xpb, hT + (size_t)c * TC2 * B_DIM * P_DIM, hstc, wchh, bchh,
                                      TC2, c == 0);
  }
  gelu_mean_k<<<dim3(P_DIM, 8), B_DIM, 0, stream>>>(hT, aggT);
  final_k<<<B_DIM, 64, 0, stream>>>(aggT, skipm, Wf, bfb, out);
}

// Round 20
// 1967.073 us; speedup vs baseline: 1.1065x; 1.1065x over previous
//
#include <hip/hip_runtime.h>

#define T_DIM 512
#define B_DIM 256
#define I_DIM 64
#define H_DIM 128
#define P_DIM 256
#define O_DIM 50

typedef _Float16 half8 __attribute__((ext_vector_type(8)));
typedef _Float16 half4 __attribute__((ext_vector_type(4)));
typedef float f32x4 __attribute__((ext_vector_type(4)));

#define GLOAD_LDS16(G, L)                                                      \
  __builtin_amdgcn_global_load_lds(                                            \
      (const __attribute__((address_space(1))) void*)(G),                      \
      (__attribute__((address_space(3))) void*)(L), 16, 0, 0)

__device__ __forceinline__ float sigm(float x) {
  return __builtin_amdgcn_rcpf(1.f + __expf(-x));
}
__device__ __forceinline__ float tanh_f(float x) {
  x = fminf(20.f, fmaxf(-20.f, x));
  float e = __expf(2.f * x);
  return (e - 1.f) * __builtin_amdgcn_rcpf(e + 1.f);
}

// ---------------- elementwise fp32 -> fp16 ----------------
__global__ void cvt_k(const float* __restrict__ s, _Float16* __restrict__ d, long n) {
  long i = (long)blockIdx.x * blockDim.x + threadIdx.x;
  long st = (long)gridDim.x * blockDim.x;
  for (; i < n; i += st) d[i] = (_Float16)s[i];
}

// fused 6-tensor weight conversion (one launch instead of six)
__global__ void cvt6_k(const float* a0, _Float16* b0, int n0, const float* a1, _Float16* b1,
                       int n1, const float* a2, _Float16* b2, int n2, const float* a3,
                       _Float16* b3, int n3, const float* a4, _Float16* b4, int n4,
                       const float* a5, _Float16* b5, int n5) {
  int i = blockIdx.x * blockDim.x + threadIdx.x;
  int st = gridDim.x * blockDim.x;
  int total = n0 + n1 + n2 + n3 + n4 + n5;
  for (; i < total; i += st) {
    int j = i;
    if (j < n0) { b0[j] = (_Float16)a0[j]; continue; }
    j -= n0;
    if (j < n1) { b1[j] = (_Float16)a1[j]; continue; }
    j -= n1;
    if (j < n2) { b2[j] = (_Float16)a2[j]; continue; }
    j -= n2;
    if (j < n3) { b3[j] = (_Float16)a3[j]; continue; }
    j -= n3;
    if (j < n4) { b4[j] = (_Float16)a4[j]; continue; }
    j -= n4;
    b5[j] = (_Float16)a5[j];
  }
}

// ---------------- fused: xmean over t + skip_mean = xmean @ Ws^T + bs ----------------
__global__ void xmean_skip_k(const float* __restrict__ x, const float* __restrict__ Wsk,
                             const float* __restrict__ bsk, float* __restrict__ skipm) {
  __shared__ float xs[4][64];
  __shared__ float xmf[64];
  const int b = blockIdx.x, tid = threadIdx.x;  // 256 threads
  const int i = tid & 63, q = tid >> 6;
  float s = 0.f;
  for (int t = q * 128; t < (q + 1) * 128; ++t) s += x[((long)t * B_DIM + b) * I_DIM + i];
  xs[q][i] = s;
  __syncthreads();
  if (tid < 64) xmf[tid] = (xs[0][tid] + xs[1][tid] + xs[2][tid] + xs[3][tid]) * (1.0f / T_DIM);
  __syncthreads();
  float acc = bsk[tid];
  for (int k = 0; k < I_DIM; ++k) acc += xmf[k] * Wsk[tid * I_DIM + k];
  skipm[b * P_DIM + tid] = acc;
}

// zero gsum/gss/aggT/flags in one launch (blocks 0-255: aggT, 256: gsum/gss, 257: flags)
__global__ void zeroAll_k(float* aggT, float* gsum, float* gss, int* flags) {
  int b = blockIdx.x, t = threadIdx.x;
  if (b < 256) {
    aggT[b * 256 + t] = 0.f;
  } else if (b == 256) {
    gsum[t] = 0.f;
    gss[t] = 0.f;
  } else if (t < 64) {
    flags[t] = 0;
  }
}

// fold BN affine into Wcih (per-column scale) + bias; BN scalars computed inline
__global__ void fold_k(const float* __restrict__ Wcih, const float* __restrict__ bcih,
                       const float* __restrict__ gsum, const float* __restrict__ gss,
                       const float* __restrict__ gamma, const float* __restrict__ beta,
                       _Float16* __restrict__ WF, float* __restrict__ bF) {
  __shared__ float red[256];
  int n = blockIdx.x, k = threadIdx.x;
  const float inv = 1.0f / ((float)T_DIM * (float)B_DIM);
  float m = gsum[k] * inv;
  float v = gss[k] * inv - m * m;
  float rs = rsqrtf(v + 1e-5f);
  float sc = gamma[k] * rs;
  float tn = beta[k] - m * sc;
  float wv = Wcih[n * 256 + k];
  WF[n * 256 + k] = (_Float16)(wv * sc);
  red[k] = wv * tn;
  __syncthreads();
  for (int s = 128; s > 0; s >>= 1) {
    if (k < s) red[k] += red[k + s];
    __syncthreads();
  }
  if (k == 0) bF[n] = bcih[n] + red[0];
}

// ---------------- fp16 MFMA GEMM: C = A[M,K] @ W[N,K]^T + bias (+bias2 n<n2lim)
// transN=0: C row-major [M][N]; if gsum!=null also accumulate BN stats per column.
// transN=1: C = [bblk][t][N][16] with M = t*256+b, bblk=b>>4  (block-major for scans)
__global__ __launch_bounds__(256) void gemm_k(
    const _Float16* __restrict__ A, const _Float16* __restrict__ W,
    const float* __restrict__ bias, const float* __restrict__ bias2, int n2lim,
    _Float16* __restrict__ C, int M, int N, int K, int transN,
    float* __restrict__ gsum, float* __restrict__ gss) {
  __shared__ __align__(16) _Float16 As[128 * 64];
  __shared__ __align__(16) _Float16 Bs[128 * 64];
  const int tid = threadIdx.x;
  const int l = tid & 63;
  const int w = tid >> 6;
  const int wr = w >> 1, wc = w & 1;
  const int lrow = l & 15, lk = l >> 4;
  const long bm = blockIdx.x, bn = blockIdx.y;

  f32x4 z = {0.f, 0.f, 0.f, 0.f};
  f32x4 acc[4][4];
#pragma unroll
  for (int m = 0; m < 4; ++m)
#pragma unroll
    for (int n = 0; n < 4; ++n) acc[m][n] = z;

  for (int k0 = 0; k0 < K; k0 += 64) {
    if (k0) __syncthreads();
#pragma unroll
    for (int it = 0; it < 4; ++it) {
      const int lin = it * 256 + tid;
      const int row = lin >> 3, slot = lin & 7;
      const int scol = (slot ^ (row & 7)) << 3;  // pre-swizzled global source
      GLOAD_LDS16(A + (bm * 128 + row) * (long)K + k0 + scol, (_Float16*)As + (size_t)lin * 8);
      GLOAD_LDS16(W + (bn * 128 + row) * (long)K + k0 + scol, (_Float16*)Bs + (size_t)lin * 8);
    }
    __syncthreads();
#pragma unroll
    for (int kk = 0; kk < 2; ++kk) {
      half8 af[4], wfr[4];
#pragma unroll
      for (int m = 0; m < 4; ++m) {
        const int row = wr * 64 + m * 16 + lrow;
        af[m] = *(const half8*)((const char*)As +
                                ((row * 128 + (kk * 32 + lk * 8) * 2) ^ ((row & 7) << 4)));
      }
#pragma unroll
      for (int n = 0; n < 4; ++n) {
        const int row = wc * 64 + n * 16 + lrow;
        wfr[n] = *(const half8*)((const char*)Bs +
                                 ((row * 128 + (kk * 32 + lk * 8) * 2) ^ ((row & 7) << 4)));
      }
#pragma unroll
      for (int m = 0; m < 4; ++m)
#pragma unroll
        for (int n = 0; n < 4; ++n)
          acc[m][n] = __builtin_amdgcn_mfma_f32_16x16x32_f16(af[m], wfr[n], acc[m][n], 0, 0, 0);
    }
  }
  if (transN) {
    const long tIdx = bm >> 1;  // B=256, 128-row tiles
    const long TCH = M >> 8;
#pragma unroll
    for (int n = 0; n < 4; ++n) {
      const int gn = (int)bn * 128 + wc * 64 + n * 16 + lrow;
      float bv = 0.f;
      if (bias) bv += bias[gn];
      if (bias2 && gn < n2lim) bv += bias2[gn];
#pragma unroll
      for (int m = 0; m < 4; ++m) {
        half4 v;
#pragma unroll
        for (int r = 0; r < 4; ++r) v[r] = (_Float16)(acc[m][n][r] + bv);
        const int blk = (int)(bm & 1) * 8 + wr * 4 + m;
        *(half4*)(C + ((blk * TCH + tIdx) * N + gn) * 16 + lk * 4) = v;
      }
    }
  } else {
#pragma unroll
    for (int n = 0; n < 4; ++n) {
      const int gn = (int)bn * 128 + wc * 64 + n * 16 + lrow;
      float bv = 0.f;
      if (bias) bv += bias[gn];
      if (bias2 && gn < n2lim) bv += bias2[gn];
      float sm = 0.f, sq = 0.f;
#pragma unroll
      for (int m = 0; m < 4; ++m)
#pragma unroll
        for (int r = 0; r < 4; ++r) {
          const long gm = bm * 128 + wr * 64 + m * 16 + lk * 4 + r;
          _Float16 pv = (_Float16)(acc[m][n][r] + bv);
          C[gm * (long)N + gn] = pv;
          float pf = (float)pv;
          sm += pf;
          sq += pf * pf;
        }
      if (gsum) {
        sm += __shfl_xor(sm, 16);
        sm += __shfl_xor(sm, 32);
        sq += __shfl_xor(sq, 16);
        sq += __shfl_xor(sq, 32);
        if (lk == 0) {
          atomicAdd(&gsum[gn], sm);
          atomicAdd(&gss[gn], sq);
        }
      }
    }
  }
}

// ---------------- producer/consumer 2-layer GRU scan across 32 blocks --------------
// Producer publishes every 32 steps (fence-cadence lever saturated at R18).
__global__ __launch_bounds__(512, 1) void scan01_pipe(
    const _Float16* __restrict__ xp0T,   // [bblk][T][384][16] incl. bih0 + bhh0(r,z)
    const _Float16* __restrict__ Whh0h,  // [384][128] fp16
    const _Float16* __restrict__ Wih1h,  // [384][128] fp16
    const _Float16* __restrict__ Whh1h,  // [384][128] fp16
    const float* __restrict__ bhh0, const float* __restrict__ bih1,
    const float* __restrict__ bhh1,
    const float* __restrict__ h0init,  // [2][B][128]
    _Float16* __restrict__ y0buf,      // [16][T][16][128]
    _Float16* __restrict__ h1buf,      // [T*256][128] row-major
    int* flags) {
  __shared__ __align__(16) _Float16 hL[2][16 * 128];
  const int tid = threadIdx.x;
  const int l = tid & 63, w = tid >> 6;  // 8 waves
  const int lrow = l & 15, lk = l >> 4;
  const int bblk = blockIdx.x & 15;
  const int rbase = bblk * 16;
  const int p = w * 16 + lrow;

  if (blockIdx.x < 16) {
    // ================= producer: layer0 =================
    half8 wf0[3][4];
#pragma unroll
    for (int g = 0; g < 3; ++g)
#pragma unroll
      for (int kk = 0; kk < 4; ++kk)
        wf0[g][kk] = *(const half8*)(Whh0h + (size_t)(g * 128 + p) * 128 + kk * 32 + lk * 8);
    const float bN0 = bhh0[2 * H_DIM + p];
    float h0r[4];
#pragma unroll
    for (int r = 0; r < 4; ++r) h0r[r] = h0init[(rbase + lk * 4 + r) * H_DIM + p];
    for (int i = tid; i < 16 * 128; i += 512) {
      int row = i >> 7, pp = i & 127;
      int byte = (row * 256 + pp * 2) ^ ((row & 7) << 4);
      *(_Float16*)((char*)hL[1] + byte) = (_Float16)h0init[(rbase + row) * H_DIM + pp];
    }
    __syncthreads();

    half4 xA[3], xB[3];
    auto loadx = [&](half4(&X)[3], int tt) {
#pragma unroll
      for (int g = 0; g < 3; ++g)
        X[g] = *(const half4*)(xp0T + (((long)bblk * T_DIM + tt) * 384 + g * 128 + p) * 16 +
                               lk * 4);
    };
    auto pstep = [&](int t, half4(&XC)[3], half4(&XN)[3]) {
      loadx(XN, (t + 1 < T_DIM) ? t + 1 : T_DIM - 1);
      char* cur = (char*)hL[(t & 1) ^ 1];
      char* nxt = (char*)hL[t & 1];
      half8 af[4];
#pragma unroll
      for (int kk = 0; kk < 4; ++kk) {
        int byte = (lrow * 256 + (kk * 32 + lk * 8) * 2) ^ ((lrow & 7) << 4);
        af[kk] = *(const half8*)(cur + byte);
      }
      f32x4 aR, aZ, aN;
#pragma unroll
      for (int r = 0; r < 4; ++r) {
        aR[r] = (float)XC[0][r];
        aZ[r] = (float)XC[1][r];
        aN[r] = 0.f;
      }
#pragma unroll
      for (int kk = 0; kk < 4; ++kk) {
        aR = __builtin_amdgcn_mfma_f32_16x16x32_f16(af[kk], wf0[0][kk], aR, 0, 0, 0);
        aZ = __builtin_amdgcn_mfma_f32_16x16x32_f16(af[kk], wf0[1][kk], aZ, 0, 0, 0);
        aN = __builtin_amdgcn_mfma_f32_16x16x32_f16(af[kk], wf0[2][kk], aN, 0, 0, 0);
      }
#pragma unroll
      for (int r = 0; r < 4; ++r) {
        float rg = sigm(aR[r]);
        float zg = sigm(aZ[r]);
        float ng = tanh_f((float)XC[2][r] + rg * (aN[r] + bN0));
        float hv = ng + zg * (h0r[r] - ng);
        h0r[r] = hv;
        int row = lk * 4 + r;
        int byte = (row * 256 + p * 2) ^ ((row & 7) << 4);
        *(_Float16*)(nxt + byte) = (_Float16)hv;
        y0buf[((size_t)(bblk * T_DIM + t) * 16 + row) * 128 + p] = (_Float16)hv;
      }
      if ((t & 31) == 31) {
        __threadfence();  // drain y0 stores (device scope) before publishing
        __syncthreads();  // all threads fenced
        if (tid == 0)
          __hip_atomic_store(&flags[bblk], t + 1, __ATOMIC_RELEASE, __HIP_MEMORY_SCOPE_AGENT);
      } else {
        __syncthreads();
      }
    };
    loadx(xA, 0);
    for (int t = 0; t < T_DIM; t += 2) {
      pstep(t, xA, xB);
      pstep(t + 1, xB, xA);
    }
  } else {
    // ================= consumer: layer1 =================
    half8 wf1x[3][4], wf1h[3][4];
#pragma unroll
    for (int g = 0; g < 3; ++g)
#pragma unroll
      for (int kk = 0; kk < 4; ++kk) {
        const size_t ro = (size_t)(g * 128 + p) * 128 + kk * 32 + lk * 8;
        wf1x[g][kk] = *(const half8*)(Wih1h + ro);
        wf1h[g][kk] = *(const half8*)(Whh1h + ro);
      }
    const float bR1 = bih1[p] + bhh1[p];
    const float bZ1 = bih1[H_DIM + p] + bhh1[H_DIM + p];
    const float bX1 = bih1[2 * H_DIM + p];
    const float bN1 = bhh1[2 * H_DIM + p];
    float h1r[4];
#pragma unroll
    for (int r = 0; r < 4; ++r)
      h1r[r] = h0init[B_DIM * H_DIM + (rbase + lk * 4 + r) * H_DIM + p];
    for (int i = tid; i < 16 * 128; i += 512) {
      int row = i >> 7, pp = i & 127;
      int byte = (row * 256 + pp * 2) ^ ((row & 7) << 4);
      *(_Float16*)((char*)hL[1] + byte) =
          (_Float16)h0init[B_DIM * H_DIM + (rbase + row) * H_DIM + pp];
    }
    __syncthreads();

    const _Float16* yb = y0buf + (size_t)bblk * T_DIM * 16 * 128;
    int avail = 0;
    auto wait_for = [&](int target) {
      if (avail < target) {
        do {
          __builtin_amdgcn_s_sleep(2);
          avail = __hip_atomic_load(&flags[bblk], __ATOMIC_ACQUIRE, __HIP_MEMORY_SCOPE_AGENT);
        } while (avail < target);
      }
    };
    auto loady = [&](half8(&Y)[4], int tt) {
#pragma unroll
      for (int kk = 0; kk < 4; ++kk)
        Y[kk] = *(const half8*)(yb + ((size_t)tt * 16 + lrow) * 128 + kk * 32 + lk * 8);
    };
    auto cstep = [&](int t, half8(&YC)[4], half8(&YN)[4]) {
      wait_for((t + 2 < T_DIM) ? (t + 2) : T_DIM);  // covers prefetch of t+1
      loady(YN, (t + 1 < T_DIM) ? t + 1 : T_DIM - 1);
      char* cur = (char*)hL[(t & 1) ^ 1];
      char* nxt = (char*)hL[t & 1];
      f32x4 aRx = {bR1, bR1, bR1, bR1};
      f32x4 aZx = {bZ1, bZ1, bZ1, bZ1};
      f32x4 aX = {bX1, bX1, bX1, bX1};
      f32x4 aRh = {0.f, 0.f, 0.f, 0.f};
      f32x4 aZh = {0.f, 0.f, 0.f, 0.f};
      f32x4 aH = {0.f, 0.f, 0.f, 0.f};
      half8 ah[4];
#pragma unroll
      for (int kk = 0; kk < 4; ++kk) {
        int byte = (lrow * 256 + (kk * 32 + lk * 8) * 2) ^ ((lrow & 7) << 4);
        ah[kk] = *(const half8*)(cur + byte);
      }
#pragma unroll
      for (int kk = 0; kk < 4; ++kk) {
        aRx = __builtin_amdgcn_mfma_f32_16x16x32_f16(YC[kk], wf1x[0][kk], aRx, 0, 0, 0);
        aZx = __builtin_amdgcn_mfma_f32_16x16x32_f16(YC[kk], wf1x[1][kk], aZx, 0, 0, 0);
        aX = __builtin_amdgcn_mfma_f32_16x16x32_f16(YC[kk], wf1x[2][kk], aX, 0, 0, 0);
        aRh = __builtin_amdgcn_mfma_f32_16x16x32_f16(ah[kk], wf1h[0][kk], aRh, 0, 0, 0);
        aZh = __builtin_amdgcn_mfma_f32_16x16x32_f16(ah[kk], wf1h[1][kk], aZh, 0, 0, 0);
        aH = __builtin_amdgcn_mfma_f32_16x16x32_f16(ah[kk], wf1h[2][kk], aH, 0, 0, 0);
      }
#pragma unroll
      for (int r = 0; r < 4; ++r) {
        float rg = sigm(aRx[r] + aRh[r]);
        float zg = sigm(aZx[r] + aZh[r]);
        float ng = tanh_f(aX[r] + rg * (aH[r] + bN1));
        float hv = ng + zg * (h1r[r] - ng);
        h1r[r] = hv;
        int row = lk * 4 + r;
        int byte = (row * 256 + p * 2) ^ ((row & 7) << 4);
        *(_Float16*)(nxt + byte) = (_Float16)hv;
        h1buf[((long)t * B_DIM + rbase + row) * 128 + p] = (_Float16)hv;
      }
      __syncthreads();
    };
    half8 yA[4], yB[4];
    wait_for(2);
    loady(yA, 0);
    for (int t = 0; t < T_DIM; t += 2) {
      cstep(t, yA, yB);
      cstep(t + 1, yB, yA);
    }
  }
}

// ---------------- GRUCell scan (P=256): 16 blocks x 8 waves ------------------------
__global__ __launch_bounds__(512, 1) void scan_cell(
    const _Float16* __restrict__ xpT,  // [bblk][TC][768][16] incl. folded biases
    _Float16* __restrict__ hT,         // [TC][256][B] (chunk-offset applied)
    float* __restrict__ hst, const _Float16* __restrict__ Whh,
    const float* __restrict__ bhh, int TC, int first) {
  __shared__ __align__(16) _Float16 hL[2][16 * 256];
  __shared__ __align__(16) _Float16 WL[768 * 64];  // K-slice [192,256) of Wchh, swizzled
  const int tid = threadIdx.x;
  const int l = tid & 63, w = tid >> 6;  // 8 waves
  const int lrow = l & 15, lk = l >> 4;
  const int rbase = blockIdx.x * 16;

  half8 wf[6][6];  // kk 0..5 resident; kk 6..7 from LDS
#pragma unroll
  for (int g = 0; g < 3; ++g)
#pragma unroll
    for (int c = 0; c < 2; ++c) {
      const int nt = g * 16 + 2 * w + c;
#pragma unroll
      for (int kk = 0; kk < 6; ++kk)
        wf[g * 2 + c][kk] =
            *(const half8*)(Whh + (size_t)(nt * 16 + lrow) * P_DIM + kk * 32 + lk * 8);
    }
  for (int q = tid; q < 768 * 8; q += 512) {
    int row = q >> 3, slot = q & 7;
    int scol = (slot ^ (row & 7)) << 3;
    *(half8*)((char*)WL + (size_t)q * 16) = *(const half8*)(Whh + (size_t)row * P_DIM + 192 + scol);
  }
  float bN[2];
#pragma unroll
  for (int c = 0; c < 2; ++c) bN[c] = bhh[2 * P_DIM + 32 * w + 16 * c + lrow];

  float h[2][4];
#pragma unroll
  for (int c = 0; c < 2; ++c)
#pragma unroll
    for (int r = 0; r < 4; ++r)
      h[c][r] = first ? 0.f : hst[(rbase + lk * 4 + r) * P_DIM + 32 * w + 16 * c + lrow];
  for (int i = tid; i < 16 * 256; i += 512) {
    int row = i >> 8, pp = i & 255;
    float hv = first ? 0.f : hst[(rbase + row) * P_DIM + pp];
    int byte = (row * 512 + pp * 2) ^ ((row & 7) << 4);
    *(_Float16*)((char*)hL[0] + byte) = (_Float16)hv;
  }
  __syncthreads();

  half4 xA[3][2], xB[3][2];
  auto loadx = [&](half4(&X)[3][2], int tt) {
#pragma unroll
    for (int g = 0; g < 3; ++g)
#pragma unroll
      for (int c = 0; c < 2; ++c)
        X[g][c] = *(const half4*)(xpT +
                                  (((long)blockIdx.x * TC + tt) * 768 + g * 256 + 32 * w + 16 * c +
                                   lrow) * 16 + lk * 4);
  };
  auto step = [&](int tt, half4(&XC)[3][2], half4(&XN)[3][2], int tn) {
    loadx(XN, tn);
    char* hCur = (char*)hL[tt & 1];
    char* hNxt = (char*)hL[(tt & 1) ^ 1];
    half8 af[4];
    f32x4 acc[3][2];
#pragma unroll
    for (int c = 0; c < 2; ++c)
#pragma unroll
      for (int r = 0; r < 4; ++r) {
        acc[0][c][r] = (float)XC[0][c][r];
        acc[1][c][r] = (float)XC[1][c][r];
        acc[2][c][r] = 0.f;
      }
#pragma unroll
    for (int kk = 0; kk < 4; ++kk) {
      int byte = (lrow * 512 + (kk * 32 + lk * 8) * 2) ^ ((lrow & 7) << 4);
      af[kk] = *(const half8*)(hCur + byte);
    }
#pragma unroll
    for (int g = 0; g < 3; ++g)
#pragma unroll
      for (int c = 0; c < 2; ++c)
#pragma unroll
        for (int kk = 0; kk < 4; ++kk)
          acc[g][c] =
              __builtin_amdgcn_mfma_f32_16x16x32_f16(af[kk], wf[g * 2 + c][kk], acc[g][c], 0, 0, 0);
#pragma unroll
    for (int kk = 0; kk < 4; ++kk) {
      int byte = (lrow * 512 + ((kk + 4) * 32 + lk * 8) * 2) ^ ((lrow & 7) << 4);
      af[kk] = *(const half8*)(hCur + byte);
    }
#pragma unroll
    for (int g = 0; g < 3; ++g)
#pragma unroll
      for (int c = 0; c < 2; ++c) {
        const int nt = g * 16 + 2 * w + c;
        const int wrow = nt * 16 + lrow;
        f32x4 a = acc[g][c];
        a = __builtin_amdgcn_mfma_f32_16x16x32_f16(af[0], wf[g * 2 + c][4], a, 0, 0, 0);
        a = __builtin_amdgcn_mfma_f32_16x16x32_f16(af[1], wf[g * 2 + c][5], a, 0, 0, 0);
        half8 w6 = *(const half8*)((char*)WL + ((wrow * 128 + lk * 16) ^ ((wrow & 7) << 4)));
        half8 w7 = *(const half8*)((char*)WL + ((wrow * 128 + 64 + lk * 16) ^ ((wrow & 7) << 4)));
        a = __builtin_amdgcn_mfma_f32_16x16x32_f16(af[2], w6, a, 0, 0, 0);
        a = __builtin_amdgcn_mfma_f32_16x16x32_f16(af[3], w7, a, 0, 0, 0);
        acc[g][c] = a;
      }
#pragma unroll
    for (int c = 0; c < 2; ++c) {
      half4 hv4;
#pragma unroll
      for (int r = 0; r < 4; ++r) {
        float rg = sigm(acc[0][c][r]);
        float zg = sigm(acc[1][c][r]);
        float ng = tanh_f((float)XC[2][c][r] + rg * (acc[2][c][r] + bN[c]));
        float hv = ng + zg * (h[c][r] - ng);
        h[c][r] = hv;
        hv4[r] = (_Float16)hv;
        const int row = lk * 4 + r, pp = 32 * w + 16 * c + lrow;
        int byte = (row * 512 + pp * 2) ^ ((row & 7) << 4);
        *(_Float16*)(hNxt + byte) = hv4[r];
      }
      *(half4*)(hT + ((long)tt * 256 + 32 * w + 16 * c + lrow) * 256 + rbase + lk * 4) = hv4;
    }
    __syncthreads();
  };
  loadx(xA, 0);
  for (int t = 0; t < TC; t += 2) {
    step(t, xA, xB, t + 1);
    step(t + 1, xB, xA, (t + 2 < TC) ? t + 2 : TC - 1);
  }
#pragma unroll
  for (int c = 0; c < 2; ++c)
#pragma unroll
    for (int r = 0; r < 4; ++r)
      hst[(rbase + lk * 4 + r) * P_DIM + 32 * w + 16 * c + lrow] = h[c][r];
}

// ---------------- gelu + mean over t (parallel over t-chunks) ----------------
__global__ void gelu_mean_k(const _Float16* __restrict__ hT, float* __restrict__ aggT) {
  int p = blockIdx.x, b = threadIdx.x;  // 256x8 blocks x 256 threads
  int t0 = blockIdx.y * 64;
  float s = 0.f;
  for (int t = t0; t < t0 + 64; ++t) {
    float v = (float)hT[((long)t * P_DIM + p) * B_DIM + b];
    s += 0.5f * v * (1.f + erff(v * 0.70710678118f));
  }
  atomicAdd(&aggT[p * B_DIM + b], s);
}

// ---------------- final: out = (aggT/T + skipm) @ Wf^T + bf ----------------
__global__ void final_k(const float* __restrict__ aggT, const float* __restrict__ skipm,
                        const float* __restrict__ Wf, const float* __restrict__ bfb,
                        float* __restrict__ out) {
  int b = blockIdx.x, o = threadIdx.x;  // 64 threads
  if (o >= O_DIM) return;
  float s = bfb[o];
  for (int p = 0; p < P_DIM; ++p)
    s += (aggT[p * B_DIM + b] * (1.0f / T_DIM) + skipm[b * P_DIM + p]) * Wf[o * P_DIM + p];
  out[b * O_DIM + o] = s;
}

extern "C" void kernel_launch(void* const* d_in, const int* in_sizes, int n_in, void* d_out,
                              int out_size, void* d_ws, size_t ws_size, hipStream_t stream) {
  const float* x = (const float*)d_in[0];
  const float* h0 = (const float*)d_in[1];
  const float* Wih0 = (const float*)d_in[2];
  const float* Whh0f = (const float*)d_in[3];
  const float* bih0 = (const float*)d_in[4];
  const float* bhh0 = (const float*)d_in[5];
  const float* Wih1 = (const float*)d_in[6];
  const float* Whh1f = (const float*)d_in[7];
  const float* bih1 = (const float*)d_in[8];
  const float* bhh1 = (const float*)d_in[9];
  const float* Wp = (const float*)d_in[10];
  const float* bp = (const float*)d_in[11];
  const float* gamma = (const float*)d_in[12];
  const float* beta = (const float*)d_in[13];
  const float* Wcih = (const float*)d_in[14];
  const float* Wchhf = (const float*)d_in[15];
  const float* bcih = (const float*)d_in[16];
  const float* bchh = (const float*)d_in[17];
  const float* Wsk = (const float*)d_in[18];
  const float* bsk = (const float*)d_in[19];
  const float* Wf = (const float*)d_in[20];
  const float* bfb = (const float*)d_in[21];
  float* out = (float*)d_out;

  char* wsp = (char*)d_ws;
  size_t off = 0;
  auto alloc = [&](size_t b) -> void* {
    void* p = wsp + off;
    off = (off + b + 255) & ~(size_t)255;
    return p;
  };
  _Float16* xh = (_Float16*)alloc((size_t)T_DIM * B_DIM * I_DIM * 2);
  _Float16* wih0 = (_Float16*)alloc(384 * 64 * 2);
  _Float16* whh0 = (_Float16*)alloc(384 * 128 * 2);
  _Float16* wih1 = (_Float16*)alloc(384 * 128 * 2);
  _Float16* whh1 = (_Float16*)alloc(384 * 128 * 2);
  _Float16* wp = (_Float16*)alloc(256 * 128 * 2);
  _Float16* wcihF = (_Float16*)alloc(768 * 256 * 2);
  _Float16* wchh = (_Float16*)alloc(768 * 256 * 2);
  _Float16* proj = (_Float16*)alloc((size_t)T_DIM * B_DIM * P_DIM * 2);  // also y0buf
  _Float16* hT = (_Float16*)alloc((size_t)T_DIM * B_DIM * P_DIM * 2);    // also h1buf
  float* hstc = (float*)alloc(B_DIM * P_DIM * 4);
  float* aggT = (float*)alloc(B_DIM * P_DIM * 4);
  float* skipm = (float*)alloc(B_DIM * P_DIM * 4);
  float* gsum = (float*)alloc(256 * 4);
  float* gss = (float*)alloc(256 * 4);
  float* bcihF = (float*)alloc(768 * 4);
  int* flags = (int*)alloc(64 * 4);

  _Float16* y0buf = proj;  // dead before gemmP writes proj
  _Float16* h1buf = hT;    // dead before scan_cell writes hT

  const size_t xp0_bytes = (size_t)T_DIM * 384 * B_DIM * 2;
  int TC2 = 512;
  while (TC2 > 32 && off + ((size_t)TC2 * B_DIM * 768 * 2 > xp0_bytes
                                ? (size_t)TC2 * B_DIM * 768 * 2
                                : xp0_bytes) >
                         ws_size)
    TC2 >>= 1;
  size_t xpb_bytes = (size_t)TC2 * B_DIM * 768 * 2;
  if (xpb_bytes < xp0_bytes) xpb_bytes = xp0_bytes;
  _Float16* xpb = (_Float16*)alloc(xpb_bytes);
  const int nc2 = T_DIM / TC2;
  const int M2 = TC2 * B_DIM;

  cvt_k<<<dim3(2048), dim3(256), 0, stream>>>(x, xh, (long)T_DIM * B_DIM * I_DIM);
  cvt6_k<<<dim3(512), dim3(256), 0, stream>>>(Wih0, wih0, 384 * 64, Whh0f, whh0, 384 * 128, Wih1,
                                              wih1, 384 * 128, Whh1f, whh1, 384 * 128, Wp, wp,
                                              256 * 128, Wchhf, wchh, 768 * 256);

  xmean_skip_k<<<B_DIM, P_DIM, 0, stream>>>(x, Wsk, bsk, skipm);
  zeroAll_k<<<dim3(258), dim3(256), 0, stream>>>(aggT, gsum, gss, flags);

  // xp0 for all T (input projection layer 0), block-major [bblk][t][384][16]
  gemm_k<<<dim3(T_DIM * B_DIM / 128, 3), 256, 0, stream>>>(
      xh, wih0, bih0, bhh0, 2 * H_DIM, xpb, T_DIM * B_DIM, 3 * H_DIM, I_DIM, 1, nullptr, nullptr);
  // producer/consumer 2-layer scan across 32 blocks
  scan01_pipe<<<32, 512, 0, stream>>>(xpb, whh0, wih1, whh1, bhh0, bih1, bhh1, h0, y0buf, h1buf,
                                      flags);
  // proj = h1 @ Wp^T + bp (row-major out) with fused BN-stats accumulation
  gemm_k<<<dim3(T_DIM * B_DIM / 128, 2), 256, 0, stream>>>(
      h1buf, wp, bp, (const float*)nullptr, 0, proj, T_DIM * B_DIM, P_DIM, H_DIM, 0, gsum, gss);
  // fold BN (scalars computed inline) into Wcih + bias
  fold_k<<<768, 256, 0, stream>>>(Wcih, bcih, gsum, gss, gamma, beta, wcihF, bcihF);
  for (int c = 0; c < nc2; ++c) {
    const _Float16* pc = proj + (size_t)c * TC2 * B_DIM * P_DIM;
    gemm_k<<<dim3(M2 / 128, 6), 256, 0, stream>>>(pc, wcihF, bcihF, bchh, 2 * P_DIM, xpb, M2,
                                                  3 * P_DIM, P_DIM, 1, nullptr, nullptr);
    scan_cell<<<16, 512, 0, stream>>>(xpb, hT + (size_t)c * TC2 * B_DIM * P_DIM, hstc, wchh, bchh,
                                      TC2, c == 0);
  }
  gelu_mean_k<<<dim3(P_DIM, 8), B_DIM, 0, stream>>>(hT, aggT);
  final_k<<<B_DIM, 64, 0, stream>>>(aggT, skipm, Wf, bfb, out);
}